// Round 1
// baseline (597.663 us; speedup 1.0000x reference)
//
#include <hip/hip_runtime.h>
#include <hip/hip_bf16.h>

#define N_NODES 12800
#define N_EDGES 204800
#define DIM 16

// ---- static device scratch (28.8 MB) -- avoids any dependence on ws_size ----
// layout (floats):
//   out   : N*16      current node features (== h)
//   aggr  : N*16      per-round message accumulator (atomics), re-zeroed each round
//   degf  : N         in-degree (float, atomic counted)
//   invd  : N         1/max(deg,1)
//   eh    : E*16      relu(edge_attr @ nn1_w.T + nn1_b)   (round-invariant)
//   A     : N*272     per-node factor: A[n][j*16+k] = sum_d out[n,d]*W2[(d*16+k)*16+j]
//                     row j=16 holds the bias term sum_d out[n,d]*nn2_b[d*16+k]
constexpr int OFF_OUT  = 0;
constexpr int OFF_AGGR = OFF_OUT  + N_NODES * 16;
constexpr int OFF_DEG  = OFF_AGGR + N_NODES * 16;
constexpr int OFF_INV  = OFF_DEG  + N_NODES;
constexpr int OFF_EH   = OFF_INV  + N_NODES;
constexpr int OFF_A    = OFF_EH   + N_EDGES * 16;
constexpr int WS_FLOATS = OFF_A + N_NODES * 272;

__device__ __align__(16) float g_ws[WS_FLOATS];

// ---------------- setup: out0 = relu(x @ lin0_w.T + lin0_b); zero aggr/deg ---
__global__ __launch_bounds__(256) void k_setup(const float* __restrict__ x,
                                               const float* __restrict__ lw,
                                               const float* __restrict__ lb) {
    int n = blockIdx.x * 256 + threadIdx.x;
    float* out  = g_ws + OFF_OUT;
    float* aggr = g_ws + OFF_AGGR;
    float* degf = g_ws + OFF_DEG;
    float x0 = x[n * 3 + 0], x1 = x[n * 3 + 1], x2 = x[n * 3 + 2];
    float v[16];
#pragma unroll
    for (int j = 0; j < 16; ++j) {
        float t = lb[j] + x0 * lw[j * 3 + 0] + x1 * lw[j * 3 + 1] + x2 * lw[j * 3 + 2];
        v[j] = fmaxf(t, 0.0f);
    }
#pragma unroll
    for (int j = 0; j < 16; j += 4) {
        *(float4*)(out + n * 16 + j)  = make_float4(v[j], v[j + 1], v[j + 2], v[j + 3]);
        *(float4*)(aggr + n * 16 + j) = make_float4(0.f, 0.f, 0.f, 0.f);
    }
    degf[n] = 0.0f;
}

// ------------- per-edge hidden: eh = relu(attr @ nn1_w.T + b); count degree --
__global__ __launch_bounds__(256) void k_edge_pre(const int* __restrict__ ei,
                                                  const float* __restrict__ attr,
                                                  const float* __restrict__ w1,
                                                  const float* __restrict__ b1) {
    int e = blockIdx.x * 256 + threadIdx.x;
    float* eh   = g_ws + OFF_EH;
    float* degf = g_ws + OFF_DEG;
    float4 a = *(const float4*)(attr + e * 4);
    float v[16];
#pragma unroll
    for (int j = 0; j < 16; ++j) {
        float t = b1[j] + a.x * w1[j * 4 + 0] + a.y * w1[j * 4 + 1] +
                  a.z * w1[j * 4 + 2] + a.w * w1[j * 4 + 3];
        v[j] = fmaxf(t, 0.0f);
    }
#pragma unroll
    for (int j = 0; j < 16; j += 4)
        *(float4*)(eh + e * 16 + j) = make_float4(v[j], v[j + 1], v[j + 2], v[j + 3]);
    atomicAdd(&degf[ei[N_EDGES + e]], 1.0f);
}

// ---------------------------------------------- invd = 1/max(deg,1) ---------
__global__ __launch_bounds__(256) void k_inv() {
    int n = blockIdx.x * 256 + threadIdx.x;
    g_ws[OFF_INV + n] = 1.0f / fmaxf(g_ws[OFF_DEG + n], 1.0f);
}

// -------- expand: A[n][j*16+k] = sum_d out[n,d]*W2t[j][d*16+k]  (j=16: bias) -
// 16 lanes per node, 16 nodes per block. W2 transposed into LDS so that the
// 16 lanes of a group read 16 consecutive floats (bank-conflict free, and the
// 4 groups of a wave broadcast the same addresses).
__global__ __launch_bounds__(256) void k_expand(const float* __restrict__ nn2_w,
                                                const float* __restrict__ nn2_b) {
    __shared__ float W2t[17 * 256];
    int tid = threadIdx.x;
    for (int m = tid; m < 17 * 256; m += 256) {
        int j = m >> 8, r = m & 255;
        W2t[m] = (j < 16) ? nn2_w[r * 16 + j] : nn2_b[r];
    }
    __syncthreads();
    const float* out = g_ws + OFF_OUT;
    float* A = g_ws + OFF_A;
    int grp = tid >> 4, k = tid & 15;
    int n = blockIdx.x * 16 + grp;
    float o[16];
#pragma unroll
    for (int d = 0; d < 16; d += 4) {
        float4 v = *(const float4*)(out + n * 16 + d);
        o[d] = v.x; o[d + 1] = v.y; o[d + 2] = v.z; o[d + 3] = v.w;
    }
    float* Arow = A + n * 272;
#pragma unroll
    for (int j = 0; j < 17; ++j) {
        const float* w = W2t + j * 256 + k;
        float acc = 0.0f;
#pragma unroll
        for (int d = 0; d < 16; ++d) acc += o[d] * w[d * 16];
        Arow[j * 16 + k] = acc;
    }
}

// --- edge: msg[e,k] = sum_j eh[e,j]*A[src][j*16+k] + A[src][256+k]; atomic ---
// 16 lanes per edge; lane k handles output k. A-row reads are 64B coalesced
// per group; eh reads broadcast within the group; atomics hit 16 consecutive
// dwords per group.
__global__ __launch_bounds__(256) void k_edge(const int* __restrict__ ei) {
    int tid = threadIdx.x;
    int el = tid >> 4, k = tid & 15;
    int e = blockIdx.x * 16 + el;
    const float* eh = g_ws + OFF_EH;
    const float* A  = g_ws + OFF_A;
    float* aggr = g_ws + OFF_AGGR;
    int s = ei[e];
    int d = ei[N_EDGES + e];
    const float* Ar = A + s * 272 + k;
    float h[16];
#pragma unroll
    for (int j = 0; j < 16; j += 4) {
        float4 v = *(const float4*)(eh + e * 16 + j);
        h[j] = v.x; h[j + 1] = v.y; h[j + 2] = v.z; h[j + 3] = v.w;
    }
    float acc = Ar[256];  // bias term (h' = 1)
#pragma unroll
    for (int j = 0; j < 16; ++j) acc += h[j] * Ar[j * 16];
    atomicAdd(&aggr[d * 16 + k], acc);
}

// ------- node update: m = relu(aggr*invd + out@conv_root + cb); GRU step -----
// one thread per node; all weights staged in LDS (all lane reads broadcast).
// Also re-zeros this node's aggr row for the next round.
__global__ __launch_bounds__(256) void k_node(const float* __restrict__ conv_root,
                                              const float* __restrict__ conv_bias,
                                              const float* __restrict__ w_ih,
                                              const float* __restrict__ w_hh,
                                              const float* __restrict__ b_ih,
                                              const float* __restrict__ b_hh,
                                              float* __restrict__ out_final,
                                              int last) {
    __shared__ float s_cr[256], s_cb[16], s_wi[768], s_wh[768], s_bi[48], s_bh[48];
    int t = threadIdx.x;
    s_cr[t] = conv_root[t];
    if (t < 16) s_cb[t] = conv_bias[t];
    for (int i = t; i < 768; i += 256) { s_wi[i] = w_ih[i]; s_wh[i] = w_hh[i]; }
    if (t < 48) { s_bi[t] = b_ih[t]; s_bh[t] = b_hh[t]; }
    __syncthreads();

    float* out  = g_ws + OFF_OUT;
    float* aggr = g_ws + OFF_AGGR;
    int n = blockIdx.x * 256 + t;
    float idg = g_ws[OFF_INV + n];

    float o[16], ag[16];
#pragma unroll
    for (int j = 0; j < 16; j += 4) {
        float4 v = *(const float4*)(out + n * 16 + j);
        o[j] = v.x; o[j + 1] = v.y; o[j + 2] = v.z; o[j + 3] = v.w;
        float4 a = *(const float4*)(aggr + n * 16 + j);
        ag[j] = a.x; ag[j + 1] = a.y; ag[j + 2] = a.z; ag[j + 3] = a.w;
        *(float4*)(aggr + n * 16 + j) = make_float4(0.f, 0.f, 0.f, 0.f);  // next round
    }

    float m[16];
#pragma unroll
    for (int j = 0; j < 16; ++j) {
        float acc = s_cb[j] + ag[j] * idg;
#pragma unroll
        for (int d = 0; d < 16; ++d) acc += o[d] * s_cr[d * 16 + j];  // out @ conv_root
        m[j] = fmaxf(acc, 0.0f);
    }

    float hn_[16];
#pragma unroll
    for (int j = 0; j < 16; ++j) {
        float ir = s_bi[j], iz = s_bi[16 + j], in_ = s_bi[32 + j];
        float hr = s_bh[j], hz = s_bh[16 + j], hh = s_bh[32 + j];
#pragma unroll
        for (int d = 0; d < 16; ++d) {
            ir  += m[d] * s_wi[j * 16 + d];
            iz  += m[d] * s_wi[(16 + j) * 16 + d];
            in_ += m[d] * s_wi[(32 + j) * 16 + d];
            hr  += o[d] * s_wh[j * 16 + d];
            hz  += o[d] * s_wh[(16 + j) * 16 + d];
            hh  += o[d] * s_wh[(32 + j) * 16 + d];
        }
        float r = 1.0f / (1.0f + __expf(-(ir + hr)));
        float z = 1.0f / (1.0f + __expf(-(iz + hz)));
        float nh = tanhf(in_ + r * hh);
        hn_[j] = (1.0f - z) * nh + z * o[j];
    }

    float* tgt = last ? out_final : out;
#pragma unroll
    for (int j = 0; j < 16; j += 4)
        *(float4*)(tgt + n * 16 + j) = make_float4(hn_[j], hn_[j + 1], hn_[j + 2], hn_[j + 3]);
}

extern "C" void kernel_launch(void* const* d_in, const int* in_sizes, int n_in,
                              void* d_out, int out_size, void* d_ws, size_t ws_size,
                              hipStream_t stream) {
    const float* x         = (const float*)d_in[0];
    const int*   ei        = (const int*)d_in[1];
    const float* edge_attr = (const float*)d_in[2];
    const float* lin0_w    = (const float*)d_in[3];
    const float* lin0_b    = (const float*)d_in[4];
    const float* nn1_w     = (const float*)d_in[5];
    const float* nn1_b     = (const float*)d_in[6];
    const float* nn2_w     = (const float*)d_in[7];
    const float* nn2_b     = (const float*)d_in[8];
    const float* conv_root = (const float*)d_in[9];
    const float* conv_bias = (const float*)d_in[10];
    const float* gru_w_ih  = (const float*)d_in[11];
    const float* gru_w_hh  = (const float*)d_in[12];
    const float* gru_b_ih  = (const float*)d_in[13];
    const float* gru_b_hh  = (const float*)d_in[14];
    float* out = (float*)d_out;

    k_setup<<<N_NODES / 256, 256, 0, stream>>>(x, lin0_w, lin0_b);
    k_edge_pre<<<N_EDGES / 256, 256, 0, stream>>>(ei, edge_attr, nn1_w, nn1_b);
    k_inv<<<N_NODES / 256, 256, 0, stream>>>();

    for (int r = 0; r < 6; ++r) {
        k_expand<<<N_NODES / 16, 256, 0, stream>>>(nn2_w, nn2_b);
        k_edge<<<N_EDGES / 16, 256, 0, stream>>>(ei);
        k_node<<<N_NODES / 256, 256, 0, stream>>>(conv_root, conv_bias, gru_w_ih,
                                                  gru_w_hh, gru_b_ih, gru_b_hh,
                                                  out, r == 5 ? 1 : 0);
    }
}

// Round 2
// 418.167 us; speedup vs baseline: 1.4292x; 1.4292x over previous
//
#include <hip/hip_runtime.h>

#define NN 12800
#define NE 204800

// ---------------- static device scratch (~30 MB) ----------------
__device__ __align__(16) float g_out[NN * 16];    // current node features h
__device__ __align__(16) float g_aggr[NN * 16];   // message accumulator (atomics)
__device__ float g_invd[NN];                      // 1/max(indeg,1)
__device__ __align__(16) float g_A[NN * 272];     // per-node factor (17 rows x 16), row16 = bias
__device__ __align__(16) float g_ehs[NE * 16];    // edge hidden, SRC-SORTED order
__device__ int g_scnt[NN];                        // src counts -> scan base -> scatter cursor
__device__ int g_dcnt[NN];                        // dst (in-)degree
__device__ int g_sdst[NE];                        // dst per sorted edge
__device__ int g_ssrc[NE];                        // src per sorted edge

// ---- S0: out0 = relu(x @ lin0_w.T + b); zero aggr / scnt / dcnt (per node) --
__global__ __launch_bounds__(256) void k_setup(const float* __restrict__ x,
                                               const float* __restrict__ lw,
                                               const float* __restrict__ lb) {
    int n = blockIdx.x * 256 + threadIdx.x;
    float x0 = x[n * 3 + 0], x1 = x[n * 3 + 1], x2 = x[n * 3 + 2];
    float v[16];
#pragma unroll
    for (int j = 0; j < 16; ++j) {
        float t = lb[j] + x0 * lw[j * 3 + 0] + x1 * lw[j * 3 + 1] + x2 * lw[j * 3 + 2];
        v[j] = fmaxf(t, 0.0f);
    }
#pragma unroll
    for (int j = 0; j < 16; j += 4) {
        *(float4*)(g_out + n * 16 + j)  = make_float4(v[j], v[j + 1], v[j + 2], v[j + 3]);
        *(float4*)(g_aggr + n * 16 + j) = make_float4(0.f, 0.f, 0.f, 0.f);
    }
    g_scnt[n] = 0;
    g_dcnt[n] = 0;
}

// ---- S1: count src / dst occurrences (per edge) ----
__global__ __launch_bounds__(256) void k_count(const int* __restrict__ ei) {
    int e = blockIdx.x * 256 + threadIdx.x;
    atomicAdd(&g_scnt[ei[e]], 1);
    atomicAdd(&g_dcnt[ei[NE + e]], 1);
}

// ---- S2: exclusive scan of g_scnt (single block); invd = 1/max(dcnt,1) ----
__global__ __launch_bounds__(256) void k_scan() {
    __shared__ int part[256];
    const int C = NN / 256;  // 50
    int t = threadIdx.x;
    int sum = 0;
    for (int i = 0; i < C; ++i) sum += g_scnt[t * C + i];
    part[t] = sum;
    __syncthreads();
    for (int off = 1; off < 256; off <<= 1) {
        int v = (t >= off) ? part[t - off] : 0;
        __syncthreads();
        part[t] += v;
        __syncthreads();
    }
    int run = (t > 0) ? part[t - 1] : 0;
    for (int i = 0; i < C; ++i) {
        int v = g_scnt[t * C + i];
        g_scnt[t * C + i] = run;
        run += v;
    }
    for (int i = t; i < NN; i += 256)
        g_invd[i] = 1.0f / fmaxf((float)g_dcnt[i], 1.0f);
}

// ---- S3: compute eh = relu(attr @ nn1_w.T + b); scatter into src-sorted slot --
__global__ __launch_bounds__(256) void k_scatter(const int* __restrict__ ei,
                                                 const float* __restrict__ attr,
                                                 const float* __restrict__ w1,
                                                 const float* __restrict__ b1) {
    int e = blockIdx.x * 256 + threadIdx.x;
    int s = ei[e], d = ei[NE + e];
    float4 a = *(const float4*)(attr + e * 4);
    float v[16];
#pragma unroll
    for (int j = 0; j < 16; ++j) {
        float t = b1[j] + a.x * w1[j * 4 + 0] + a.y * w1[j * 4 + 1] +
                  a.z * w1[j * 4 + 2] + a.w * w1[j * 4 + 3];
        v[j] = fmaxf(t, 0.0f);
    }
    int pos = atomicAdd(&g_scnt[s], 1);
    g_sdst[pos] = d;
    g_ssrc[pos] = s;
#pragma unroll
    for (int j = 0; j < 16; j += 4)
        *(float4*)(g_ehs + pos * 16 + j) = make_float4(v[j], v[j + 1], v[j + 2], v[j + 3]);
}

// ---- A0: A[n][j*16+k] = sum_d out[n,d]*W2t[j][d*16+k]; row j=16 is bias ----
__global__ __launch_bounds__(256) void k_expand(const float* __restrict__ nn2_w,
                                                const float* __restrict__ nn2_b) {
    __shared__ float W2t[17 * 256];
    int tid = threadIdx.x;
    for (int m = tid; m < 17 * 256; m += 256) {
        int j = m >> 8, r = m & 255;
        W2t[m] = (j < 16) ? nn2_w[r * 16 + j] : nn2_b[r];
    }
    __syncthreads();
    int grp = tid >> 4, k = tid & 15;
    int n = blockIdx.x * 16 + grp;
    float o[16];
#pragma unroll
    for (int d = 0; d < 16; d += 4) {
        float4 v = *(const float4*)(g_out + n * 16 + d);
        o[d] = v.x; o[d + 1] = v.y; o[d + 2] = v.z; o[d + 3] = v.w;
    }
    float* Arow = g_A + n * 272;
#pragma unroll
    for (int j = 0; j < 17; ++j) {
        float acc = 0.0f;
#pragma unroll
        for (int d = 0; d < 16; ++d) acc += o[d] * W2t[j * 256 + d * 16 + k];
        Arow[j * 16 + k] = acc;
    }
}

// ---- edge: sorted order; msg = eh . A[src] + bias; atomic into aggr[dst] ----
__global__ __launch_bounds__(256) void k_edge() {
    int tid = threadIdx.x;
    int grp = tid >> 4, k = tid & 15;
    int p = blockIdx.x * 16 + grp;  // sorted edge slot (ascending src)
    int s = g_ssrc[p];
    int d = g_sdst[p];
    float h[16];
#pragma unroll
    for (int j = 0; j < 16; j += 4) {
        float4 v = *(const float4*)(g_ehs + p * 16 + j);
        h[j] = v.x; h[j + 1] = v.y; h[j + 2] = v.z; h[j + 3] = v.w;
    }
    const float* Ar = g_A + s * 272 + k;
    float acc = Ar[256];  // bias row
#pragma unroll
    for (int j = 0; j < 16; ++j) acc += h[j] * Ar[j * 16];
    atomicAdd(&g_aggr[d * 16 + k], acc);
}

// ---- node update + A for next round, fused. 16 lanes/node, 16 nodes/block. --
__global__ __launch_bounds__(256) void k_nodeA(const float* __restrict__ cr,
                                               const float* __restrict__ cb,
                                               const float* __restrict__ wi,
                                               const float* __restrict__ wh,
                                               const float* __restrict__ bi,
                                               const float* __restrict__ bh,
                                               const float* __restrict__ nn2_w,
                                               const float* __restrict__ nn2_b,
                                               float* __restrict__ out_final,
                                               int last) {
    __shared__ float s_cr[256], s_wiT[768], s_whT[768], s_W2t[17 * 256];
    __shared__ float s_cb[16], s_bi[48], s_bh[48], s_m[256];
    int t = threadIdx.x;
    s_cr[t] = cr[t];  // s_cr[d*16+k] = conv_root[d][k] (already the layout we want)
    for (int i = t; i < 768; i += 256) {
        int row = i >> 4, d = i & 15;           // w[row,d]
        s_wiT[d * 48 + row] = wi[i];            // transposed: lane-k reads consecutive
        s_whT[d * 48 + row] = wh[i];
    }
    for (int i = t; i < 17 * 256; i += 256) {
        int j = i >> 8, r = i & 255;
        s_W2t[i] = (j < 16) ? nn2_w[r * 16 + j] : nn2_b[r];
    }
    if (t < 16) s_cb[t] = cb[t];
    if (t < 48) { s_bi[t] = bi[t]; s_bh[t] = bh[t]; }
    __syncthreads();

    int grp = t >> 4, k = t & 15;
    int n = blockIdx.x * 16 + grp;
    float o[16];
#pragma unroll
    for (int d = 0; d < 16; d += 4) {
        float4 v = *(const float4*)(g_out + n * 16 + d);  // broadcast within group
        o[d] = v.x; o[d + 1] = v.y; o[d + 2] = v.z; o[d + 3] = v.w;
    }
    float ag = g_aggr[n * 16 + k];
    g_aggr[n * 16 + k] = 0.0f;  // re-zero for next round
    float idg = g_invd[n];

    float acc = s_cb[k] + ag * idg;
#pragma unroll
    for (int d = 0; d < 16; ++d) acc += o[d] * s_cr[d * 16 + k];
    float m = fmaxf(acc, 0.0f);
    s_m[grp * 16 + k] = m;
    __syncthreads();

    float md[16];
#pragma unroll
    for (int d = 0; d < 16; ++d) md[d] = s_m[grp * 16 + d];
    float ir = s_bi[k], iz = s_bi[16 + k], in_ = s_bi[32 + k];
    float hr = s_bh[k], hz = s_bh[16 + k], hh = s_bh[32 + k];
#pragma unroll
    for (int d = 0; d < 16; ++d) {
        ir  += md[d] * s_wiT[d * 48 + k];
        iz  += md[d] * s_wiT[d * 48 + 16 + k];
        in_ += md[d] * s_wiT[d * 48 + 32 + k];
        hr  += o[d] * s_whT[d * 48 + k];
        hz  += o[d] * s_whT[d * 48 + 16 + k];
        hh  += o[d] * s_whT[d * 48 + 32 + k];
    }
    float r = 1.0f / (1.0f + __expf(-(ir + hr)));
    float z = 1.0f / (1.0f + __expf(-(iz + hz)));
    float nh = tanhf(in_ + r * hh);
    float hnew = (1.0f - z) * nh + z * o[k];

    if (last) {
        out_final[n * 16 + k] = hnew;
    } else {
        g_out[n * 16 + k] = hnew;
        __syncthreads();            // s_m reads above are done
        s_m[grp * 16 + k] = hnew;
        __syncthreads();
        float on[16];
#pragma unroll
        for (int d = 0; d < 16; ++d) on[d] = s_m[grp * 16 + d];
        float* Arow = g_A + n * 272;
#pragma unroll
        for (int j = 0; j < 17; ++j) {
            float a2 = 0.0f;
#pragma unroll
            for (int d = 0; d < 16; ++d) a2 += on[d] * s_W2t[j * 256 + d * 16 + k];
            Arow[j * 16 + k] = a2;
        }
    }
}

extern "C" void kernel_launch(void* const* d_in, const int* in_sizes, int n_in,
                              void* d_out, int out_size, void* d_ws, size_t ws_size,
                              hipStream_t stream) {
    const float* x         = (const float*)d_in[0];
    const int*   ei        = (const int*)d_in[1];
    const float* edge_attr = (const float*)d_in[2];
    const float* lin0_w    = (const float*)d_in[3];
    const float* lin0_b    = (const float*)d_in[4];
    const float* nn1_w     = (const float*)d_in[5];
    const float* nn1_b     = (const float*)d_in[6];
    const float* nn2_w     = (const float*)d_in[7];
    const float* nn2_b     = (const float*)d_in[8];
    const float* conv_root = (const float*)d_in[9];
    const float* conv_bias = (const float*)d_in[10];
    const float* gru_w_ih  = (const float*)d_in[11];
    const float* gru_w_hh  = (const float*)d_in[12];
    const float* gru_b_ih  = (const float*)d_in[13];
    const float* gru_b_hh  = (const float*)d_in[14];
    float* out = (float*)d_out;

    k_setup<<<NN / 256, 256, 0, stream>>>(x, lin0_w, lin0_b);
    k_count<<<NE / 256, 256, 0, stream>>>(ei);
    k_scan<<<1, 256, 0, stream>>>();
    k_scatter<<<NE / 256, 256, 0, stream>>>(ei, edge_attr, nn1_w, nn1_b);
    k_expand<<<NN / 16, 256, 0, stream>>>(nn2_w, nn2_b);

    for (int r = 0; r < 6; ++r) {
        k_edge<<<NE / 16, 256, 0, stream>>>();
        k_nodeA<<<NN / 16, 256, 0, stream>>>(conv_root, conv_bias, gru_w_ih, gru_w_hh,
                                             gru_b_ih, gru_b_hh, nn2_w, nn2_b,
                                             out, r == 5 ? 1 : 0);
    }
}